// Round 2
// baseline (696.824 us; speedup 1.0000x reference)
//
#include <hip/hip_runtime.h>
#include <math.h>

// PatchCore-DINOv2 anomaly score, round 2.
// prep (normalize) -> score (bf16 MFMA; 1 block per 128-row bank panel x 4 q-passes;
// mb_local read ~once from HBM; XOR-swizzled LDS, wave tile 128x64) ->
// rmin (coalesced per-q min) -> refine (parallel candidate scan + exact f32 on 32-row subchunks)
// -> gmin/out (global branch + combine).
// bf16 bound: |delta(msq-2dot)| <= ~0.12; EPS=0.25 (2x margin) -> result exact.

#define D 384
#define PQ 256      // q rows per score block
#define TNP 128     // bank rows per panel
#define BK 64       // k-chunk elems
#define KC 6        // 384/64

typedef __attribute__((ext_vector_type(8))) short short8v;
typedef __attribute__((ext_vector_type(4))) float f32x4;

static __device__ __forceinline__ unsigned short f2bf(float f) {
  unsigned u = __float_as_uint(f);
  unsigned r = 0x7FFFu + ((u >> 16) & 1u);   // round-to-nearest-even
  return (unsigned short)((u + r) >> 16);
}
static __device__ __forceinline__ unsigned pack2(float lo, float hi) {
  return (unsigned)f2bf(lo) | ((unsigned)f2bf(hi) << 16);
}

// ---------------- prep: L2-normalize patches + globals ----------------
__global__ void prep_kernel(const float* __restrict__ patches,
                            const float* __restrict__ globals_x,
                            float* __restrict__ pf32,
                            unsigned short* __restrict__ pbf,
                            float* __restrict__ psq,
                            float* __restrict__ gf32,
                            float* __restrict__ gsq,
                            int Q) {
  const int row = blockIdx.x;
  const int lane = threadIdx.x;  // 64 threads = 1 wave
  const float* src = (row < Q) ? (patches + (size_t)row * D)
                               : (globals_x + (size_t)(row - Q) * D);
  float v[6];
  float ss = 0.f;
#pragma unroll
  for (int j = 0; j < 6; ++j) { v[j] = src[lane + 64 * j]; ss += v[j] * v[j]; }
#pragma unroll
  for (int d = 1; d < 64; d <<= 1) ss += __shfl_xor(ss, d);
  const float inv = 1.f / (sqrtf(ss) + 1e-12f);
  float pn[6]; float ps = 0.f;
#pragma unroll
  for (int j = 0; j < 6; ++j) { pn[j] = v[j] * inv; ps += pn[j] * pn[j]; }
#pragma unroll
  for (int d = 1; d < 64; d <<= 1) ps += __shfl_xor(ps, d);
  if (row < Q) {
#pragma unroll
    for (int j = 0; j < 6; ++j) {
      pf32[(size_t)row * D + lane + 64 * j] = pn[j];
      pbf[(size_t)row * D + lane + 64 * j] = f2bf(pn[j]);
    }
    if (lane == 0) psq[row] = ps;
  } else {
    const int b = row - Q;
#pragma unroll
    for (int j = 0; j < 6; ++j) gf32[(size_t)b * D + lane + 64 * j] = pn[j];
    if (lane == 0) gsq[b] = ps;
  }
}

// ---------------- score: grid (NPAN, 4). block = 256q x 128n panel ----------------
// LDS linear [rows][64] bf16 with slot-swizzle sigma = s ^ ((row>>2)&7): conflict-free
// frag reads and (near-)conflict-free staging writes.
__global__ __launch_bounds__(256, 2) void score_kernel(
    const float* __restrict__ mbl,
    const unsigned short* __restrict__ pbf,
    float* __restrict__ tilemin,   // [NSUB][Q], sub-chunk = 32 bank rows
    int Q, int N) {
  __shared__ alignas(16) unsigned short lA[PQ * BK];   // 32 KB
  __shared__ alignas(16) unsigned short lB[TNP * BK];  // 16 KB
  __shared__ float msqH[TNP * 2];
  __shared__ float msqF[TNP];

  const int tid = threadIdx.x;
  const int lane = tid & 63;
  const int wid = tid >> 6;
  const int wq = wid >> 1;   // 0..1 : q half (128 rows)
  const int wn = wid & 1;    // 0..1 : n half (64 rows)
  const int nb = blockIdx.x;
  const int qp = blockIdx.y;
  const int nbase = nb * TNP;
  const int qbase = qp * PQ;

  // A staging: thread t owns A row t (8 x 16B slots per k-chunk)
  const int asw = (tid >> 2) & 7;
  const unsigned short* aptr = pbf + (size_t)(qbase + tid) * D;
  unsigned short* awr = &lA[tid * BK];

  // B staging: thread t owns B row t>>1, half t&1 (4 slots per k-chunk)
  const int brow = tid >> 1;
  const int bh = tid & 1;
  const int bsw = (brow >> 2) & 7;
  const int gn = nbase + brow;
  const bool nvalid = gn < N;
  const float* bptr = mbl + (size_t)(nvalid ? gn : 0) * D;
  unsigned short* bwr = &lB[brow * BK];

  const int fr = lane & 15;
  const int g = lane >> 4;

  f32x4 acc[8][4];
#pragma unroll
  for (int i = 0; i < 8; ++i)
#pragma unroll
    for (int j = 0; j < 4; ++j) acc[i][j] = (f32x4){0.f, 0.f, 0.f, 0.f};
  float msqreg = 0.f;

  for (int kc = 0; kc < KC; ++kc) {
    __syncthreads();
    // ---- stage A: 8 x 16B (source slot s -> LDS slot s^asw) ----
#pragma unroll
    for (int s = 0; s < 8; ++s) {
      uint4 v = *(const uint4*)(aptr + kc * BK + (s << 3));
      *(uint4*)(awr + ((s ^ asw) << 3)) = v;
    }
    // ---- stage B: convert f32->bf16, fold msq ----
#pragma unroll
    for (int i = 0; i < 4; ++i) {
      const int s = (bh << 2) | i;
      float4 f0, f1;
      if (nvalid) {
        f0 = *(const float4*)(bptr + kc * BK + (s << 3));
        f1 = *(const float4*)(bptr + kc * BK + (s << 3) + 4);
      } else {
        f0 = (float4){0.f,0.f,0.f,0.f}; f1 = f0;
      }
      msqreg += f0.x*f0.x + f0.y*f0.y + f0.z*f0.z + f0.w*f0.w
              + f1.x*f1.x + f1.y*f1.y + f1.z*f1.z + f1.w*f1.w;
      uint4 w = { pack2(f0.x,f0.y), pack2(f0.z,f0.w), pack2(f1.x,f1.y), pack2(f1.z,f1.w) };
      *(uint4*)(bwr + ((s ^ bsw) << 3)) = w;
    }
    __syncthreads();
    // ---- compute: 2 k-steps of 32, 8x4 frags ----
#pragma unroll
    for (int ks = 0; ks < 2; ++ks) {
      const int s = (ks << 2) | g;
      short8v b[4];
#pragma unroll
      for (int nf = 0; nf < 4; ++nf) {
        const int r = wn * 64 + nf * 16 + fr;
        b[nf] = *(const short8v*)(&lB[r * BK + ((s ^ ((r >> 2) & 7)) << 3)]);
      }
#pragma unroll
      for (int mf = 0; mf < 8; ++mf) {
        const int r = wq * 128 + mf * 16 + fr;
        short8v av = *(const short8v*)(&lA[r * BK + ((s ^ ((r >> 2) & 7)) << 3)]);
#pragma unroll
        for (int nf = 0; nf < 4; ++nf)
          acc[mf][nf] = __builtin_amdgcn_mfma_f32_16x16x32_bf16(av, b[nf], acc[mf][nf], 0, 0, 0);
      }
    }
  }

  // ---- msq finalize ----
  msqH[tid] = msqreg;          // [row][half] = [2r+h] = tid
  __syncthreads();
  if (tid < TNP) msqF[tid] = (nbase + tid < N) ? (msqH[2 * tid] + msqH[2 * tid + 1]) : 1e30f;
  __syncthreads();

  float mq[4];
#pragma unroll
  for (int nf = 0; nf < 4; ++nf) mq[nf] = msqF[wn * 64 + nf * 16 + fr];

  // ---- per-(q, 32-row subchunk) min; C layout: col=lane&15 (n), row=g*4+j (q) ----
#pragma unroll
  for (int mf = 0; mf < 8; ++mf) {
#pragma unroll
    for (int j = 0; j < 4; ++j) {
      float v0 = fminf(mq[0] - 2.f * acc[mf][0][j], mq[1] - 2.f * acc[mf][1][j]);
      float v1 = fminf(mq[2] - 2.f * acc[mf][2][j], mq[3] - 2.f * acc[mf][3][j]);
#pragma unroll
      for (int d2 = 1; d2 < 16; d2 <<= 1) {
        v0 = fminf(v0, __shfl_xor(v0, d2));
        v1 = fminf(v1, __shfl_xor(v1, d2));
      }
      if (fr == 0) {
        const int q = qbase + wq * 128 + mf * 16 + g * 4 + j;
        tilemin[(size_t)(nb * 4 + wn * 2 + 0) * Q + q] = v0;
        tilemin[(size_t)(nb * 4 + wn * 2 + 1) * Q + q] = v1;
      }
    }
  }
}

// ---------------- rmin: coalesced partial min over subchunk rows ----------------
__global__ void rmin_kernel(const float* __restrict__ tilemin,
                            float* __restrict__ gpart,
                            int Q, int NSUB) {
  const int q = blockIdx.x * 128 + threadIdx.x;
  const int s = blockIdx.y;
  const int sl = (NSUB + 3) >> 2;
  const int r1 = min(NSUB, (s + 1) * sl);
  float m = 1e30f;
  for (int r = s * sl; r < r1; ++r) m = fminf(m, tilemin[(size_t)r * Q + q]);
  gpart[s * Q + q] = m;
}

__device__ __forceinline__ float block_min(float v, float* red) {
#pragma unroll
  for (int d = 1; d < 64; d <<= 1) v = fminf(v, __shfl_xor(v, d));
  if ((threadIdx.x & 63) == 0) red[threadIdx.x >> 6] = v;
  __syncthreads();
  const float r = fminf(fminf(red[0], red[1]), fminf(red[2], red[3]));
  __syncthreads();
  return r;
}
__device__ __forceinline__ float block_max(float v, float* red) {
#pragma unroll
  for (int d = 1; d < 64; d <<= 1) v = fmaxf(v, __shfl_xor(v, d));
  if ((threadIdx.x & 63) == 0) red[threadIdx.x >> 6] = v;
  __syncthreads();
  const float r = fmaxf(fmaxf(red[0], red[1]), fmaxf(red[2], red[3]));
  __syncthreads();
  return r;
}

// ---------------- refine: parallel candidate scan + exact f32 ----------------
__global__ __launch_bounds__(256) void refine_kernel(
    const float* __restrict__ mbl,
    const float* __restrict__ pf32,
    const float* __restrict__ psq,
    const float* __restrict__ tilemin,
    const float* __restrict__ gpart,
    float* __restrict__ dmin,
    int Q, int N, int NSUB) {
  __shared__ int cnt;
  __shared__ int cand[64];
  __shared__ float red[4];
  const int q = blockIdx.x;
  const int tid = threadIdx.x;
  if (tid == 0) cnt = 0;
  __syncthreads();
  const float gm = fminf(fminf(gpart[q], gpart[Q + q]),
                         fminf(gpart[2 * Q + q], gpart[3 * Q + q]));
  const float thr = gm + 0.25f;   // 2x margin over worst-case bf16 dot error
  for (int r = tid; r < NSUB; r += 256) {
    if (tilemin[(size_t)r * Q + q] <= thr) {
      int i = atomicAdd(&cnt, 1);
      if (i < 64) cand[i] = r;
    }
  }
  __syncthreads();
  const int nc = min(cnt, 64);

  const int row8 = tid >> 3, oct = tid & 7;
  const float* prow = pf32 + (size_t)q * D + oct * 48;
  float4 pr[12];
#pragma unroll
  for (int i = 0; i < 12; ++i) pr[i] = *(const float4*)(prow + i * 4);

  float best = 1e30f;
  for (int c = 0; c < nc; ++c) {
    const int n = cand[c] * 32 + row8;
    float v;
    if (n < N) {
      const float* mr = mbl + (size_t)n * D + oct * 48;
      float dot = 0.f, ms = 0.f;
#pragma unroll
      for (int i = 0; i < 12; ++i) {
        float4 a = *(const float4*)(mr + i * 4);
        dot += a.x*pr[i].x + a.y*pr[i].y + a.z*pr[i].z + a.w*pr[i].w;
        ms  += a.x*a.x + a.y*a.y + a.z*a.z + a.w*a.w;
      }
      v = ms - 2.f * dot;
    } else {
      v = 1e30f;
    }
#pragma unroll
    for (int d2 = 1; d2 < 8; d2 <<= 1) {
      // sum partial (ms - 2dot) over the 8 octs (linear in partials)
      float o = __shfl_xor(v, d2);
      v = (n < N) ? v + o : 1e30f;
    }
    best = fminf(best, v);
  }
  best = block_min(best, red);
  if (tid == 0) dmin[q] = sqrtf(fmaxf(psq[q] + best, 0.f));
}

// ---------------- global branch: partial min over mb_global slices ----------------
__global__ __launch_bounds__(256) void gmin_kernel(
    const float* __restrict__ mbg,
    const float* __restrict__ gf32,
    const float* __restrict__ gsq,
    float* __restrict__ gpartG,
    int M) {
  __shared__ float red[4];
  const int b = blockIdx.x, s = blockIdx.y;
  const int tid = threadIdx.x;
  const int sl = (M + 7) >> 3;
  const int row = s * sl + tid;
  const float* g = gf32 + (size_t)b * D;
  float v = 1e30f;
  if (tid < sl && row < M) {
    const float* mr = mbg + (size_t)row * D;
    float dot = 0.f, ms = 0.f;
#pragma unroll 4
    for (int k = 0; k < D; k += 4) {
      float4 a = *(const float4*)(mr + k);
      float4 p = *(const float4*)(g + k);
      dot += a.x*p.x + a.y*p.y + a.z*p.z + a.w*p.w;
      ms  += a.x*a.x + a.y*a.y + a.z*a.z + a.w*a.w;
    }
    v = gsq[b] + ms - 2.f * dot;
  }
  v = block_min(v, red);
  if (tid == 0) gpartG[b * 8 + s] = v;
}

// ---------------- combine ----------------
__global__ __launch_bounds__(256) void out_kernel(
    const float* __restrict__ gpartG,
    const float* __restrict__ dmin,
    float* __restrict__ out,
    int P) {
  __shared__ float red[4];
  const int b = blockIdx.x;
  const int tid = threadIdx.x;
  float v = (tid < P) ? dmin[(size_t)b * P + tid] : -1e30f;
  const float local = block_max(v, red);
  float gm = (tid < 8) ? gpartG[b * 8 + tid] : 1e30f;
  gm = block_min(gm, red);
  if (tid == 0) out[b] = 0.7f * local + 0.3f * sqrtf(fmaxf(gm, 0.f));
}

extern "C" void kernel_launch(void* const* d_in, const int* in_sizes, int n_in,
                              void* d_out, int out_size, void* d_ws, size_t ws_size,
                              hipStream_t stream) {
  const float* patches   = (const float*)d_in[0];
  const float* globals_x = (const float*)d_in[1];
  const float* mbl       = (const float*)d_in[2];
  const float* mbg       = (const float*)d_in[3];
  float* out = (float*)d_out;

  const int Q = in_sizes[0] / D;          // 1024
  const int B = in_sizes[1] / D;          // 4
  const int N = in_sizes[2] / D;          // 100000
  const int M = in_sizes[3] / D;          // 2000
  const int P = Q / B;                    // 256
  const int NPAN = (N + TNP - 1) / TNP;   // 782
  const int NSUB = NPAN * 4;              // 3128

  char* w = (char*)d_ws;
  auto alloc = [&](size_t bytes) {
    char* p = w;
    w += (bytes + 255) & ~(size_t)255;
    return p;
  };
  float*          pf32    = (float*)alloc((size_t)Q * D * sizeof(float));
  unsigned short* pbf     = (unsigned short*)alloc((size_t)Q * D * sizeof(unsigned short));
  float*          psq     = (float*)alloc((size_t)Q * sizeof(float));
  float*          gf32    = (float*)alloc((size_t)B * D * sizeof(float));
  float*          gsqp    = (float*)alloc((size_t)B * sizeof(float));
  float*          tilemin = (float*)alloc((size_t)NSUB * Q * sizeof(float));
  float*          gpart   = (float*)alloc((size_t)4 * Q * sizeof(float));
  float*          gpartG  = (float*)alloc((size_t)B * 8 * sizeof(float));
  float*          dmin    = (float*)alloc((size_t)Q * sizeof(float));

  prep_kernel<<<Q + B, 64, 0, stream>>>(patches, globals_x, pf32, pbf, psq, gf32, gsqp, Q);
  score_kernel<<<dim3(NPAN, 4), 256, 0, stream>>>(mbl, pbf, tilemin, Q, N);
  rmin_kernel<<<dim3(Q / 128, 4), 128, 0, stream>>>(tilemin, gpart, Q, NSUB);
  refine_kernel<<<Q, 256, 0, stream>>>(mbl, pf32, psq, tilemin, gpart, dmin, Q, N, NSUB);
  gmin_kernel<<<dim3(B, 8), 256, 0, stream>>>(mbg, gf32, gsqp, gpartG, M);
  out_kernel<<<B, 256, 0, stream>>>(gpartG, dmin, out, P);
}

// Round 5
// 517.624 us; speedup vs baseline: 1.3462x; 1.3462x over previous
//
#include <hip/hip_runtime.h>
#include <math.h>

// PatchCore-DINOv2 anomaly score, round 5 (hardened round-3 design).
// score: A (queries, bf16, L2-resident) fragments DIRECT from global;
//        B (bank panel) f32->bf16 reg-staged into padded LDS (LROW=72), double-buffered
//        with literal buffer indices (no runtime-indexed pointer arrays);
//        wave tile 128q x 64n (8x4 frags), grid (4 q-passes fast, 782 panels).
// tail:  LDS-tiled transpose -> coalesced refine scans; exact f32 refine.
// safety: hard ws_size guard; if base footprint doesn't fit, use a <3MB fallback
//         (score reduces straight to per-q min, no refine) so we never write OOB.

#define D 384
#define PQ 256
#define TNP 128
#define BK 64
#define NCH 6       // 384/64
#define LROW 72     // 144B row stride: bank start advances 4/row -> 2-way frag reads (free)

typedef __attribute__((ext_vector_type(8))) short short8v;
typedef __attribute__((ext_vector_type(4))) float f32x4;

static __device__ __forceinline__ unsigned short f2bf(float f) {
  unsigned u = __float_as_uint(f);
  unsigned r = 0x7FFFu + ((u >> 16) & 1u);   // RNE
  return (unsigned short)((u + r) >> 16);
}
static __device__ __forceinline__ unsigned pack2(float lo, float hi) {
  return (unsigned)f2bf(lo) | ((unsigned)f2bf(hi) << 16);
}

// ---------------- prep ----------------
__global__ void prep_kernel(const float* __restrict__ patches,
                            const float* __restrict__ globals_x,
                            float* __restrict__ pf32,
                            unsigned short* __restrict__ pbf,
                            float* __restrict__ psq,
                            float* __restrict__ gf32,
                            float* __restrict__ gsq,
                            int Q) {
  const int row = blockIdx.x;
  const int lane = threadIdx.x;  // 64 = 1 wave
  const float* src = (row < Q) ? (patches + (size_t)row * D)
                               : (globals_x + (size_t)(row - Q) * D);
  float v[6];
  float ss = 0.f;
#pragma unroll
  for (int j = 0; j < 6; ++j) { v[j] = src[lane + 64 * j]; ss += v[j] * v[j]; }
#pragma unroll
  for (int d = 1; d < 64; d <<= 1) ss += __shfl_xor(ss, d);
  const float inv = 1.f / (sqrtf(ss) + 1e-12f);
  float pn[6]; float ps = 0.f;
#pragma unroll
  for (int j = 0; j < 6; ++j) { pn[j] = v[j] * inv; ps += pn[j] * pn[j]; }
#pragma unroll
  for (int d = 1; d < 64; d <<= 1) ps += __shfl_xor(ps, d);
  if (row < Q) {
#pragma unroll
    for (int j = 0; j < 6; ++j) {
      pf32[(size_t)row * D + lane + 64 * j] = pn[j];
      pbf[(size_t)row * D + lane + 64 * j] = f2bf(pn[j]);
    }
    if (lane == 0) psq[row] = ps;
  } else {
    const int b = row - Q;
#pragma unroll
    for (int j = 0; j < 6; ++j) gf32[(size_t)b * D + lane + 64 * j] = pn[j];
    if (lane == 0) gsq[b] = ps;
  }
}

// ---------------- score (templated output mode) ----------------
// MODE 0: write per-(q, 32-row subchunk) mins to tilemin[NSUBP][Q]  (main path)
// MODE 1: atomicMin-style reduce into per-q d2min via atomic CAS-free trick:
//         we instead write per-(q,panel) min to a [4][Q] slot with atomic fminf emulation.
__device__ __forceinline__ void atomic_fmin(float* addr, float val) {
  // d2 values are >= -psq > -2; bias to positive then use atomicMin on uint ordering
  unsigned* ua = (unsigned*)addr;
  float cur = __uint_as_float(atomicAdd(ua, 0u));  // relaxed read
  while (val < cur) {
    unsigned assumed = __float_as_uint(cur);
    unsigned old = atomicCAS(ua, assumed, __float_as_uint(val));
    if (old == assumed) break;
    cur = __uint_as_float(old);
  }
}

template <int MODE>
__global__ __launch_bounds__(256, 2) void score_kernel(
    const float* __restrict__ mbl,
    const unsigned short* __restrict__ pbf,
    float* __restrict__ tilemin,   // MODE0: [NSUBP][Q]; MODE1: [Q] (pre-init to +inf)
    int Q, int N) {
  __shared__ alignas(16) unsigned short lB0[TNP * LROW];
  __shared__ alignas(16) unsigned short lB1[TNP * LROW];
  __shared__ float msqH[TNP * 2];
  __shared__ float msqF[TNP];

  const int tid = threadIdx.x;
  const int lane = tid & 63;
  const int wid = tid >> 6;
  const int wq = wid >> 1;
  const int wn = wid & 1;
  const int qp = blockIdx.x;     // q-pass FAST: 4 blocks of same panel temporally adjacent
  const int nb = blockIdx.y;
  const int qbase = qp * PQ;
  const int nbase = nb * TNP;
  const int fr = lane & 15;
  const int g = lane >> 4;

  const int brow = tid >> 1, h = tid & 1;
  const int gn = nbase + brow;
  const bool nvalid = gn < N;
  const float* bptr = mbl + (size_t)(nvalid ? gn : 0) * D + h * 32;
  const int boff = brow * LROW + h * 32;

  const unsigned short* abase = pbf + (size_t)(qbase + wq * 128 + fr) * D + g * 8;

  f32x4 acc[8][4];
#pragma unroll
  for (int i = 0; i < 8; ++i)
#pragma unroll
    for (int j = 0; j < 4; ++j) acc[i][j] = (f32x4){0.f, 0.f, 0.f, 0.f};
  float msqreg = 0.f;

  // stage chunk kc into dst (literal-addressed)
  auto stage = [&](int kc, unsigned short* dst) {
    const float* src = bptr + kc * BK;
    uint4 w[4];
    if (nvalid) {
      float s = 0.f;
#pragma unroll
      for (int i = 0; i < 4; ++i) {
        float4 f0 = *(const float4*)(src + i * 8);
        float4 f1 = *(const float4*)(src + i * 8 + 4);
        s += f0.x*f0.x + f0.y*f0.y + f0.z*f0.z + f0.w*f0.w
           + f1.x*f1.x + f1.y*f1.y + f1.z*f1.z + f1.w*f1.w;
        w[i] = (uint4){ pack2(f0.x,f0.y), pack2(f0.z,f0.w), pack2(f1.x,f1.y), pack2(f1.z,f1.w) };
      }
      msqreg += s;
    } else {
#pragma unroll
      for (int i = 0; i < 4; ++i) w[i] = (uint4){0u,0u,0u,0u};
    }
#pragma unroll
    for (int i = 0; i < 4; ++i) *(uint4*)(dst + boff + i * 8) = w[i];
  };

  auto compute = [&](int kc, const unsigned short* buf) {
#pragma unroll
    for (int ks = 0; ks < 2; ++ks) {
      short8v b[4];
#pragma unroll
      for (int nf = 0; nf < 4; ++nf)
        b[nf] = *(const short8v*)(&buf[(wn * 64 + nf * 16 + fr) * LROW + (ks * 4 + g) * 8]);
#pragma unroll
      for (int mf = 0; mf < 8; ++mf) {
        short8v av = *(const short8v*)(abase + (size_t)mf * 16 * D + kc * BK + ks * 32);
#pragma unroll
        for (int nf = 0; nf < 4; ++nf)
          acc[mf][nf] = __builtin_amdgcn_mfma_f32_16x16x32_bf16(av, b[nf], acc[mf][nf], 0, 0, 0);
      }
    }
  };

  // 2-phase unrolled double-buffered k-loop; all buffer refs are literals
  stage(0, lB0);
  __syncthreads();
  stage(1, lB1);        // writes lB1 while nobody reads it
  compute(0, lB0);
  __syncthreads();
  stage(2, lB0);
  compute(1, lB1);
  __syncthreads();
  stage(3, lB1);
  compute(2, lB0);
  __syncthreads();
  stage(4, lB0);
  compute(3, lB1);
  __syncthreads();
  stage(5, lB1);
  compute(4, lB0);
  __syncthreads();
  compute(5, lB1);
  __syncthreads();      // protect msqH reuse below

  msqH[tid] = msqreg;
  __syncthreads();
  if (tid < TNP) msqF[tid] = (nbase + tid < N) ? (msqH[2 * tid] + msqH[2 * tid + 1]) : 1e30f;
  __syncthreads();

  float mq[4];
#pragma unroll
  for (int nf = 0; nf < 4; ++nf) mq[nf] = msqF[wn * 64 + nf * 16 + fr];

#pragma unroll
  for (int mf = 0; mf < 8; ++mf) {
#pragma unroll
    for (int j = 0; j < 4; ++j) {
      float v0 = fminf(mq[0] - 2.f * acc[mf][0][j], mq[1] - 2.f * acc[mf][1][j]);
      float v1 = fminf(mq[2] - 2.f * acc[mf][2][j], mq[3] - 2.f * acc[mf][3][j]);
#pragma unroll
      for (int d2 = 1; d2 < 16; d2 <<= 1) {
        v0 = fminf(v0, __shfl_xor(v0, d2));
        v1 = fminf(v1, __shfl_xor(v1, d2));
      }
      if (fr == 0) {
        const int q = qbase + wq * 128 + mf * 16 + g * 4 + j;
        if (MODE == 0) {
          tilemin[(size_t)(nb * 4 + wn * 2 + 0) * Q + q] = v0;
          tilemin[(size_t)(nb * 4 + wn * 2 + 1) * Q + q] = v1;
        } else {
          atomic_fmin(&tilemin[q], fminf(v0, v1));
        }
      }
    }
  }
}

// ---------------- init for MODE1 fallback ----------------
__global__ void init_inf_kernel(float* __restrict__ p, int n) {
  int i = blockIdx.x * 256 + threadIdx.x;
  if (i < n) p[i] = 1e30f;
}
// d2min[q] (bf16-approx) -> dmin[q] final (no refine; used only in low-ws fallback)
__global__ void final_dmin_kernel(const float* __restrict__ d2min,
                                  const float* __restrict__ psq,
                                  float* __restrict__ dmin, int Q) {
  int q = blockIdx.x * 256 + threadIdx.x;
  if (q < Q) dmin[q] = sqrtf(fmaxf(psq[q] + d2min[q], 0.f));
}

// ---------------- transpose tilemin [NSUBP][Q] -> [Q][NSUBP] ----------------
__global__ __launch_bounds__(256) void transpose_kernel(
    const float* __restrict__ tm, float* __restrict__ tmT, int Q, int NSUBP) {
  __shared__ float t[64][65];
  const int tx = threadIdx.x & 63, ty = threadIdx.x >> 6;
  const int qb = blockIdx.x * 64, sb = blockIdx.y * 64;
#pragma unroll
  for (int i = 0; i < 64; i += 4)
    t[i + ty][tx] = tm[(size_t)(sb + i + ty) * Q + qb + tx];
  __syncthreads();
#pragma unroll
  for (int i = 0; i < 64; i += 4)
    tmT[(size_t)(qb + i + ty) * NSUBP + sb + tx] = t[tx][i + ty];
}

__device__ __forceinline__ float block_min(float v, float* red) {
#pragma unroll
  for (int d = 1; d < 64; d <<= 1) v = fminf(v, __shfl_xor(v, d));
  if ((threadIdx.x & 63) == 0) red[threadIdx.x >> 6] = v;
  __syncthreads();
  const float r = fminf(fminf(red[0], red[1]), fminf(red[2], red[3]));
  __syncthreads();
  return r;
}
__device__ __forceinline__ float block_max(float v, float* red) {
#pragma unroll
  for (int d = 1; d < 64; d <<= 1) v = fmaxf(v, __shfl_xor(v, d));
  if ((threadIdx.x & 63) == 0) red[threadIdx.x >> 6] = v;
  __syncthreads();
  const float r = fmaxf(fmaxf(red[0], red[1]), fmaxf(red[2], red[3]));
  __syncthreads();
  return r;
}

// ---------------- refine (main path) ----------------
__global__ __launch_bounds__(256) void refine_kernel(
    const float* __restrict__ mbl,
    const float* __restrict__ pf32,
    const float* __restrict__ psq,
    const float* __restrict__ tmT,   // [Q][NSUBP]
    float* __restrict__ dmin,
    int Q, int N, int NSUB, int NSUBP) {
  __shared__ int cnt;
  __shared__ int cand[64];
  __shared__ float red[4];
  const int q = blockIdx.x;
  const int tid = threadIdx.x;
  if (tid == 0) cnt = 0;
  __syncthreads();

  const float* rowp = tmT + (size_t)q * NSUBP;
  float m = 1e30f;
  for (int r = tid; r < NSUB; r += 256) m = fminf(m, rowp[r]);
  const float gm = block_min(m, red);
  const float thr = gm + 0.25f;   // 2x margin over worst-case bf16 dot error

  for (int r = tid; r < NSUB; r += 256)
    if (rowp[r] <= thr) { int i = atomicAdd(&cnt, 1); if (i < 64) cand[i] = r; }
  __syncthreads();
  const int nc = min(cnt, 64);

  const int row8 = tid >> 3, oct = tid & 7;
  const float* prow = pf32 + (size_t)q * D + oct * 48;
  float4 pr[12];
#pragma unroll
  for (int i = 0; i < 12; ++i) pr[i] = *(const float4*)(prow + i * 4);

  float best = 1e30f;
  for (int c = 0; c < nc; ++c) {
    const int n = cand[c] * 32 + row8;
    float v;
    if (n < N) {
      const float* mr = mbl + (size_t)n * D + oct * 48;
      float dot = 0.f, ms = 0.f;
#pragma unroll
      for (int i = 0; i < 12; ++i) {
        float4 a = *(const float4*)(mr + i * 4);
        dot += a.x*pr[i].x + a.y*pr[i].y + a.z*pr[i].z + a.w*pr[i].w;
        ms  += a.x*a.x + a.y*a.y + a.z*a.z + a.w*a.w;
      }
      v = ms - 2.f * dot;
    } else {
      v = 1e30f;
    }
#pragma unroll
    for (int d2 = 1; d2 < 8; d2 <<= 1) {
      float o = __shfl_xor(v, d2);
      v = (n < N) ? v + o : 1e30f;
    }
    best = fminf(best, v);
  }
  best = block_min(best, red);
  if (tid == 0) dmin[q] = sqrtf(fmaxf(psq[q] + best, 0.f));
}

// ---------------- global branch partials ----------------
__global__ __launch_bounds__(256) void gmin_kernel(
    const float* __restrict__ mbg,
    const float* __restrict__ gf32,
    const float* __restrict__ gsq,
    float* __restrict__ gpartG,
    int M) {
  __shared__ float red[4];
  const int b = blockIdx.x, s = blockIdx.y;
  const int tid = threadIdx.x;
  const int sl = (M + 31) / 32;
  const int row = s * sl + tid;
  const float* g = gf32 + (size_t)b * D;
  float v = 1e30f;
  if (tid < sl && row < M) {
    const float* mr = mbg + (size_t)row * D;
    float dot = 0.f, ms = 0.f;
#pragma unroll 4
    for (int k = 0; k < D; k += 4) {
      float4 a = *(const float4*)(mr + k);
      float4 p = *(const float4*)(g + k);
      dot += a.x*p.x + a.y*p.y + a.z*p.z + a.w*p.w;
      ms  += a.x*a.x + a.y*a.y + a.z*a.z + a.w*a.w;
    }
    v = gsq[b] + ms - 2.f * dot;
  }
  v = block_min(v, red);
  if (tid == 0) gpartG[b * 32 + s] = v;
}

// ---------------- combine ----------------
__global__ __launch_bounds__(256) void out_kernel(
    const float* __restrict__ gpartG,
    const float* __restrict__ dmin,
    float* __restrict__ out,
    int P) {
  __shared__ float red[4];
  const int b = blockIdx.x;
  const int tid = threadIdx.x;
  float v = (tid < P) ? dmin[(size_t)b * P + tid] : -1e30f;
  const float local = block_max(v, red);
  float gm = (tid < 32) ? gpartG[b * 32 + tid] : 1e30f;
  gm = block_min(gm, red);
  if (tid == 0) out[b] = 0.7f * local + 0.3f * sqrtf(fmaxf(gm, 0.f));
}

extern "C" void kernel_launch(void* const* d_in, const int* in_sizes, int n_in,
                              void* d_out, int out_size, void* d_ws, size_t ws_size,
                              hipStream_t stream) {
  const float* patches   = (const float*)d_in[0];
  const float* globals_x = (const float*)d_in[1];
  const float* mbl       = (const float*)d_in[2];
  const float* mbg       = (const float*)d_in[3];
  float* out = (float*)d_out;

  const int Q = in_sizes[0] / D;          // 1024
  const int B = in_sizes[1] / D;          // 4
  const int N = in_sizes[2] / D;          // 100000
  const int M = in_sizes[3] / D;          // 2000
  const int P = Q / B;                    // 256
  const int NPAN = (N + TNP - 1) / TNP;   // 782
  const int NSUB = NPAN * 4;              // 3128
  const int NSUBP = ((NSUB + 63) / 64) * 64;  // 3136
  const int QP = (Q + PQ - 1) / PQ;       // 4

  char* w = (char*)d_ws;
  char* wend = (char*)d_ws + ws_size;
  auto alloc = [&](size_t bytes) {
    char* p = w;
    w += (bytes + 255) & ~(size_t)255;
    return p;
  };
  // small common allocations (< 2.4 MB)
  float*          pf32   = (float*)alloc((size_t)Q * D * sizeof(float));
  unsigned short* pbf    = (unsigned short*)alloc((size_t)Q * D * sizeof(unsigned short));
  float*          psq    = (float*)alloc((size_t)Q * sizeof(float));
  float*          gf32   = (float*)alloc((size_t)B * D * sizeof(float));
  float*          gsqp   = (float*)alloc((size_t)B * sizeof(float));
  float*          dmin   = (float*)alloc((size_t)Q * sizeof(float));
  float*          gpartG = (float*)alloc((size_t)B * 32 * sizeof(float));
  float*          d2min  = (float*)alloc((size_t)Q * sizeof(float));
  if (w > wend) return;  // cannot run at all; harness will report mismatch, not corruption

  const size_t tm_bytes = (size_t)NSUBP * Q * sizeof(float);
  const int full = (w + 2 * ((tm_bytes + 255) & ~(size_t)255) <= wend) ? 1 : 0;

  prep_kernel<<<Q + B, 64, 0, stream>>>(patches, globals_x, pf32, pbf, psq, gf32, gsqp, Q);

  if (full) {
    float* tilemin  = (float*)alloc(tm_bytes);
    float* tileminT = (float*)alloc(tm_bytes);
    score_kernel<0><<<dim3(QP, NPAN), 256, 0, stream>>>(mbl, pbf, tilemin, Q, N);
    transpose_kernel<<<dim3(Q / 64, NSUBP / 64), 256, 0, stream>>>(tilemin, tileminT, Q, NSUBP);
    refine_kernel<<<Q, 256, 0, stream>>>(mbl, pf32, psq, tileminT, dmin, Q, N, NSUB, NSUBP);
  } else {
    // low-ws fallback: bf16-approx distances straight to per-q min (no refine)
    init_inf_kernel<<<(Q + 255) / 256, 256, 0, stream>>>(d2min, Q);
    score_kernel<1><<<dim3(QP, NPAN), 256, 0, stream>>>(mbl, pbf, d2min, Q, N);
    final_dmin_kernel<<<(Q + 255) / 256, 256, 0, stream>>>(d2min, psq, dmin, Q);
  }

  gmin_kernel<<<dim3(B, 32), 256, 0, stream>>>(mbg, gf32, gsqp, gpartG, M);
  out_kernel<<<B, 256, 0, stream>>>(gpartG, dmin, out, P);
}

// Round 9
// 491.679 us; speedup vs baseline: 1.4172x; 1.0528x over previous
//
#include <hip/hip_runtime.h>
#include <math.h>

// PatchCore-DINOv2 anomaly score, round 9 (= round 6 source; third resubmission —
// rounds 6-8 all died to GPUAcquisitionTimeout before compile/run; no HW evidence yet).
// score: T14 split-stage (issue-early/write-late) double-buffered B staging;
//        A-frags (8/chunk) prefetched to regs BEFORE B-loads so counted vmcnt
//        never drains the in-flight HBM prefetch; wave tile 64q x 128n;
//        bijective XCD swizzle (qp-fast) so each bank panel is HBM-fetched once.
// tail:  transpose -> coalesced refine scans; exact f32 refine (thr = gm+0.25).

#define D 384
#define PQ 256      // q rows per block
#define TNP 128     // bank rows per panel
#define BK 64       // k elems per chunk
#define LROW 72     // 144B LDS row stride: 2-way frag reads (free)

typedef __attribute__((ext_vector_type(8))) short short8v;
typedef __attribute__((ext_vector_type(4))) float f32x4;

static __device__ __forceinline__ unsigned short f2bf(float f) {
  unsigned u = __float_as_uint(f);
  unsigned r = 0x7FFFu + ((u >> 16) & 1u);   // RNE
  return (unsigned short)((u + r) >> 16);
}
static __device__ __forceinline__ unsigned pack2(float lo, float hi) {
  return (unsigned)f2bf(lo) | ((unsigned)f2bf(hi) << 16);
}

// ---------------- prep ----------------
__global__ void prep_kernel(const float* __restrict__ patches,
                            const float* __restrict__ globals_x,
                            float* __restrict__ pf32,
                            unsigned short* __restrict__ pbf,
                            float* __restrict__ psq,
                            float* __restrict__ gf32,
                            float* __restrict__ gsq,
                            int Q) {
  const int row = blockIdx.x;
  const int lane = threadIdx.x;  // 64 = 1 wave
  const float* src = (row < Q) ? (patches + (size_t)row * D)
                               : (globals_x + (size_t)(row - Q) * D);
  float v[6];
  float ss = 0.f;
#pragma unroll
  for (int j = 0; j < 6; ++j) { v[j] = src[lane + 64 * j]; ss += v[j] * v[j]; }
#pragma unroll
  for (int d = 1; d < 64; d <<= 1) ss += __shfl_xor(ss, d);
  const float inv = 1.f / (sqrtf(ss) + 1e-12f);
  float pn[6]; float ps = 0.f;
#pragma unroll
  for (int j = 0; j < 6; ++j) { pn[j] = v[j] * inv; ps += pn[j] * pn[j]; }
#pragma unroll
  for (int d = 1; d < 64; d <<= 1) ps += __shfl_xor(ps, d);
  if (row < Q) {
#pragma unroll
    for (int j = 0; j < 6; ++j) {
      pf32[(size_t)row * D + lane + 64 * j] = pn[j];
      pbf[(size_t)row * D + lane + 64 * j] = f2bf(pn[j]);
    }
    if (lane == 0) psq[row] = ps;
  } else {
    const int b = row - Q;
#pragma unroll
    for (int j = 0; j < 6; ++j) gf32[(size_t)b * D + lane + 64 * j] = pn[j];
    if (lane == 0) gsq[b] = ps;
  }
}

__device__ __forceinline__ void atomic_fmin(float* addr, float val) {
  unsigned* ua = (unsigned*)addr;
  float cur = __uint_as_float(atomicAdd(ua, 0u));
  while (val < cur) {
    unsigned assumed = __float_as_uint(cur);
    unsigned old = atomicCAS(ua, assumed, __float_as_uint(val));
    if (old == assumed) break;
    cur = __uint_as_float(old);
  }
}

// ---------------- score ----------------
// MODE 0: tilemin[NSUB][Q] subchunk mins (main). MODE 1: atomic per-q min (low-ws fallback).
template <int MODE>
__global__ __launch_bounds__(256, 2) void score_kernel(
    const float* __restrict__ mbl,
    const unsigned short* __restrict__ pbf,
    float* __restrict__ tilemin,
    int Q, int N, int QP, int q8, int r8) {
  __shared__ alignas(16) unsigned short lB0[TNP * LROW];
  __shared__ alignas(16) unsigned short lB1[TNP * LROW];
  __shared__ float msqH[TNP * 2];
  __shared__ float msqF[TNP];

  const int tid = threadIdx.x;
  const int lane = tid & 63;
  const int wid = tid >> 6;          // wave = 64q sub-tile
  const int fr = lane & 15;
  const int g = lane >> 4;

  // bijective XCD swizzle (m204): HW dispatch id -> logical wg, qp-fast
  const int flat = blockIdx.x;
  const int xcd = flat & 7, idx = flat >> 3;
  const int wg = (xcd < r8 ? xcd * (q8 + 1) : r8 * (q8 + 1) + (xcd - r8) * q8) + idx;
  const int nb = wg / QP;
  const int qp = wg - nb * QP;
  const int qbase = qp * PQ;
  const int nbase = nb * TNP;

  // B staging: thread t -> row t>>1, half t&1 (32 f32 per chunk)
  const int brow = tid >> 1, h = tid & 1;
  const int gn = nbase + brow;
  const float* bptr = mbl + (size_t)((gn < N) ? gn : 0) * D + h * 32;
  const int boff = brow * LROW + h * 32;

  // A: row = qbase + wid*64 + mf*16 + fr; elem = kc*64 + ks*32 + g*8
  const unsigned short* abase = pbf + (size_t)(qbase + wid * 64 + fr) * D + g * 8;

  f32x4 acc[4][8];
#pragma unroll
  for (int i = 0; i < 4; ++i)
#pragma unroll
    for (int j = 0; j < 8; ++j) acc[i][j] = (f32x4){0.f, 0.f, 0.f, 0.f};
  float msqreg = 0.f;
  float4 breg[8];
  short8v a[8];

  auto bload = [&](int kc) {
    const float* src = bptr + kc * BK;
#pragma unroll
    for (int i = 0; i < 8; ++i) breg[i] = *(const float4*)(src + i * 4);
  };
  auto bwrite = [&](unsigned short* base) {
    float s = 0.f;
    uint4 w[4];
#pragma unroll
    for (int i = 0; i < 4; ++i) {
      float4 f0 = breg[2 * i], f1 = breg[2 * i + 1];
      s += f0.x*f0.x + f0.y*f0.y + f0.z*f0.z + f0.w*f0.w
         + f1.x*f1.x + f1.y*f1.y + f1.z*f1.z + f1.w*f1.w;
      w[i] = (uint4){ pack2(f0.x,f0.y), pack2(f0.z,f0.w), pack2(f1.x,f1.y), pack2(f1.z,f1.w) };
    }
#pragma unroll
    for (int i = 0; i < 4; ++i) *(uint4*)(base + boff + i * 8) = w[i];
    msqreg += s;
  };
  auto aload = [&](int kc) {
#pragma unroll
    for (int ks = 0; ks < 2; ++ks)
#pragma unroll
      for (int mf = 0; mf < 4; ++mf)
        a[ks * 4 + mf] = *(const short8v*)(abase + (size_t)mf * 16 * D + kc * BK + ks * 32);
  };
  auto compute = [&](const unsigned short* buf) {
#pragma unroll
    for (int ks = 0; ks < 2; ++ks) {
      short8v b[8];
#pragma unroll
      for (int nf = 0; nf < 8; ++nf)
        b[nf] = *(const short8v*)(&buf[(nf * 16 + fr) * LROW + (ks * 4 + g) * 8]);
#pragma unroll
      for (int mf = 0; mf < 4; ++mf)
#pragma unroll
        for (int nf = 0; nf < 8; ++nf)
          acc[mf][nf] = __builtin_amdgcn_mfma_f32_16x16x32_bf16(a[ks * 4 + mf], b[nf],
                                                                acc[mf][nf], 0, 0, 0);
    }
  };

  // prologue
  bload(0);
  bwrite(lB0);
  __syncthreads();
  // phases: [A-loads(k); B-loads(k+1); compute(k) (counted vmcnt on A only);
  //          vmcnt(0)+convert+write(k+1); barrier]
  aload(0); bload(1); compute(lB0); bwrite(lB1); __syncthreads();
  aload(1); bload(2); compute(lB1); bwrite(lB0); __syncthreads();
  aload(2); bload(3); compute(lB0); bwrite(lB1); __syncthreads();
  aload(3); bload(4); compute(lB1); bwrite(lB0); __syncthreads();
  aload(4); bload(5); compute(lB0); bwrite(lB1); __syncthreads();
  aload(5);           compute(lB1);              __syncthreads();

  // msq finalize (invalid rows -> +inf regardless of staged duplicates)
  msqH[tid] = msqreg;
  __syncthreads();
  if (tid < TNP) msqF[tid] = (nbase + tid < N) ? (msqH[2 * tid] + msqH[2 * tid + 1]) : 1e30f;
  __syncthreads();

  float mq[8];
#pragma unroll
  for (int nf = 0; nf < 8; ++nf) mq[nf] = msqF[nf * 16 + fr];

  // per-(q, 32-row subchunk) min; C: n = fr (within nf*16), q = g*4 + j
#pragma unroll
  for (int mf = 0; mf < 4; ++mf) {
#pragma unroll
    for (int j = 0; j < 4; ++j) {
      float v[4];
#pragma unroll
      for (int s = 0; s < 4; ++s)
        v[s] = fminf(mq[2 * s] - 2.f * acc[mf][2 * s][j],
                     mq[2 * s + 1] - 2.f * acc[mf][2 * s + 1][j]);
#pragma unroll
      for (int d2 = 1; d2 < 16; d2 <<= 1)
#pragma unroll
        for (int s = 0; s < 4; ++s) v[s] = fminf(v[s], __shfl_xor(v[s], d2));
      if (fr == 0) {
        const int q = qbase + wid * 64 + mf * 16 + g * 4 + j;
        if (MODE == 0) {
#pragma unroll
          for (int s = 0; s < 4; ++s)
            tilemin[(size_t)(nb * 4 + s) * Q + q] = v[s];
        } else {
          atomic_fmin(&tilemin[q],
                      fminf(fminf(v[0], v[1]), fminf(v[2], v[3])));
        }
      }
    }
  }
}

// ---------------- fallback helpers ----------------
__global__ void init_inf_kernel(float* __restrict__ p, int n) {
  int i = blockIdx.x * 256 + threadIdx.x;
  if (i < n) p[i] = 1e30f;
}
__global__ void final_dmin_kernel(const float* __restrict__ d2min,
                                  const float* __restrict__ psq,
                                  float* __restrict__ dmin, int Q) {
  int q = blockIdx.x * 256 + threadIdx.x;
  if (q < Q) dmin[q] = sqrtf(fmaxf(psq[q] + d2min[q], 0.f));
}

// ---------------- transpose [NSUBP][Q] -> [Q][NSUBP] ----------------
__global__ __launch_bounds__(256) void transpose_kernel(
    const float* __restrict__ tm, float* __restrict__ tmT, int Q, int NSUBP) {
  __shared__ float t[64][65];
  const int tx = threadIdx.x & 63, ty = threadIdx.x >> 6;
  const int qb = blockIdx.x * 64, sb = blockIdx.y * 64;
#pragma unroll
  for (int i = 0; i < 64; i += 4)
    t[i + ty][tx] = tm[(size_t)(sb + i + ty) * Q + qb + tx];
  __syncthreads();
#pragma unroll
  for (int i = 0; i < 64; i += 4)
    tmT[(size_t)(qb + i + ty) * NSUBP + sb + tx] = t[tx][i + ty];
}

__device__ __forceinline__ float block_min(float v, float* red) {
#pragma unroll
  for (int d = 1; d < 64; d <<= 1) v = fminf(v, __shfl_xor(v, d));
  if ((threadIdx.x & 63) == 0) red[threadIdx.x >> 6] = v;
  __syncthreads();
  const float r = fminf(fminf(red[0], red[1]), fminf(red[2], red[3]));
  __syncthreads();
  return r;
}
__device__ __forceinline__ float block_max(float v, float* red) {
#pragma unroll
  for (int d = 1; d < 64; d <<= 1) v = fmaxf(v, __shfl_xor(v, d));
  if ((threadIdx.x & 63) == 0) red[threadIdx.x >> 6] = v;
  __syncthreads();
  const float r = fmaxf(fmaxf(red[0], red[1]), fmaxf(red[2], red[3]));
  __syncthreads();
  return r;
}

// ---------------- refine ----------------
__global__ __launch_bounds__(256) void refine_kernel(
    const float* __restrict__ mbl,
    const float* __restrict__ pf32,
    const float* __restrict__ psq,
    const float* __restrict__ tmT,   // [Q][NSUBP]
    float* __restrict__ dmin,
    int Q, int N, int NSUB, int NSUBP) {
  __shared__ int cnt;
  __shared__ int cand[64];
  __shared__ float red[4];
  const int q = blockIdx.x;
  const int tid = threadIdx.x;
  if (tid == 0) cnt = 0;
  __syncthreads();

  const float* rowp = tmT + (size_t)q * NSUBP;
  float m = 1e30f;
  for (int r = tid; r < NSUB; r += 256) m = fminf(m, rowp[r]);
  const float gm = block_min(m, red);
  const float thr = gm + 0.25f;   // 2x margin over worst-case bf16 dot error

  for (int r = tid; r < NSUB; r += 256)
    if (rowp[r] <= thr) { int i = atomicAdd(&cnt, 1); if (i < 64) cand[i] = r; }
  __syncthreads();
  const int nc = min(cnt, 64);

  const int row8 = tid >> 3, oct = tid & 7;
  const float* prow = pf32 + (size_t)q * D + oct * 48;
  float4 pr[12];
#pragma unroll
  for (int i = 0; i < 12; ++i) pr[i] = *(const float4*)(prow + i * 4);

  float best = 1e30f;
  for (int c = 0; c < nc; ++c) {
    const int n = cand[c] * 32 + row8;
    float v;
    if (n < N) {
      const float* mr = mbl + (size_t)n * D + oct * 48;
      float dot = 0.f, ms = 0.f;
#pragma unroll
      for (int i = 0; i < 12; ++i) {
        float4 aa = *(const float4*)(mr + i * 4);
        dot += aa.x*pr[i].x + aa.y*pr[i].y + aa.z*pr[i].z + aa.w*pr[i].w;
        ms  += aa.x*aa.x + aa.y*aa.y + aa.z*aa.z + aa.w*aa.w;
      }
      v = ms - 2.f * dot;
    } else {
      v = 1e30f;
    }
#pragma unroll
    for (int d2 = 1; d2 < 8; d2 <<= 1) {
      float o = __shfl_xor(v, d2);
      v = (n < N) ? v + o : 1e30f;
    }
    best = fminf(best, v);
  }
  best = block_min(best, red);
  if (tid == 0) dmin[q] = sqrtf(fmaxf(psq[q] + best, 0.f));
}

// ---------------- global branch ----------------
__global__ __launch_bounds__(256) void gmin_kernel(
    const float* __restrict__ mbg,
    const float* __restrict__ gf32,
    const float* __restrict__ gsq,
    float* __restrict__ gpartG,
    int M) {
  __shared__ float red[4];
  const int b = blockIdx.x, s = blockIdx.y;
  const int tid = threadIdx.x;
  const int sl = (M + 31) / 32;
  const int row = s * sl + tid;
  const float* g = gf32 + (size_t)b * D;
  float v = 1e30f;
  if (tid < sl && row < M) {
    const float* mr = mbg + (size_t)row * D;
    float dot = 0.f, ms = 0.f;
#pragma unroll 4
    for (int k = 0; k < D; k += 4) {
      float4 aa = *(const float4*)(mr + k);
      float4 p = *(const float4*)(g + k);
      dot += aa.x*p.x + aa.y*p.y + aa.z*p.z + aa.w*p.w;
      ms  += aa.x*aa.x + aa.y*aa.y + aa.z*aa.z + aa.w*aa.w;
    }
    v = gsq[b] + ms - 2.f * dot;
  }
  v = block_min(v, red);
  if (tid == 0) gpartG[b * 32 + s] = v;
}

// ---------------- combine ----------------
__global__ __launch_bounds__(256) void out_kernel(
    const float* __restrict__ gpartG,
    const float* __restrict__ dmin,
    float* __restrict__ out,
    int P) {
  __shared__ float red[4];
  const int b = blockIdx.x;
  const int tid = threadIdx.x;
  float v = (tid < P) ? dmin[(size_t)b * P + tid] : -1e30f;
  const float local = block_max(v, red);
  float gm = (tid < 32) ? gpartG[b * 32 + tid] : 1e30f;
  gm = block_min(gm, red);
  if (tid == 0) out[b] = 0.7f * local + 0.3f * sqrtf(fmaxf(gm, 0.f));
}

extern "C" void kernel_launch(void* const* d_in, const int* in_sizes, int n_in,
                              void* d_out, int out_size, void* d_ws, size_t ws_size,
                              hipStream_t stream) {
  const float* patches   = (const float*)d_in[0];
  const float* globals_x = (const float*)d_in[1];
  const float* mbl       = (const float*)d_in[2];
  const float* mbg       = (const float*)d_in[3];
  float* out = (float*)d_out;

  const int Q = in_sizes[0] / D;          // 1024
  const int B = in_sizes[1] / D;          // 4
  const int N = in_sizes[2] / D;          // 100000
  const int M = in_sizes[3] / D;          // 2000
  const int P = Q / B;                    // 256
  const int NPAN = (N + TNP - 1) / TNP;   // 782
  const int NSUB = NPAN * 4;              // 3128
  const int NSUBP = ((NSUB + 63) / 64) * 64;  // 3136
  const int QP = (Q + PQ - 1) / PQ;       // 4
  const int nwg = QP * NPAN;              // 3128
  const int q8 = nwg / 8, r8 = nwg % 8;

  char* w = (char*)d_ws;
  char* wend = (char*)d_ws + ws_size;
  auto alloc = [&](size_t bytes) {
    char* p = w;
    w += (bytes + 255) & ~(size_t)255;
    return p;
  };
  float*          pf32   = (float*)alloc((size_t)Q * D * sizeof(float));
  unsigned short* pbf    = (unsigned short*)alloc((size_t)Q * D * sizeof(unsigned short));
  float*          psq    = (float*)alloc((size_t)Q * sizeof(float));
  float*          gf32   = (float*)alloc((size_t)B * D * sizeof(float));
  float*          gsqp   = (float*)alloc((size_t)B * sizeof(float));
  float*          dmin   = (float*)alloc((size_t)Q * sizeof(float));
  float*          gpartG = (float*)alloc((size_t)B * 32 * sizeof(float));
  float*          d2min  = (float*)alloc((size_t)Q * sizeof(float));
  if (w > wend) return;

  const size_t tm_bytes = (size_t)NSUBP * Q * sizeof(float);
  const int full = (w + 2 * ((tm_bytes + 255) & ~(size_t)255) <= wend) ? 1 : 0;

  prep_kernel<<<Q + B, 64, 0, stream>>>(patches, globals_x, pf32, pbf, psq, gf32, gsqp, Q);

  if (full) {
    float* tilemin  = (float*)alloc(tm_bytes);
    float* tileminT = (float*)alloc(tm_bytes);
    score_kernel<0><<<nwg, 256, 0, stream>>>(mbl, pbf, tilemin, Q, N, QP, q8, r8);
    transpose_kernel<<<dim3(Q / 64, NSUBP / 64), 256, 0, stream>>>(tilemin, tileminT, Q, NSUBP);
    refine_kernel<<<Q, 256, 0, stream>>>(mbl, pf32, psq, tileminT, dmin, Q, N, NSUB, NSUBP);
  } else {
    init_inf_kernel<<<(Q + 255) / 256, 256, 0, stream>>>(d2min, Q);
    score_kernel<1><<<nwg, 256, 0, stream>>>(mbl, pbf, d2min, Q, N, QP, q8, r8);
    final_dmin_kernel<<<(Q + 255) / 256, 256, 0, stream>>>(d2min, psq, dmin, Q);
  }

  gmin_kernel<<<dim3(B, 32), 256, 0, stream>>>(mbg, gf32, gsqp, gpartG, M);
  out_kernel<<<B, 256, 0, stream>>>(gpartG, dmin, out, P);
}

// Round 10
// 457.371 us; speedup vs baseline: 1.5235x; 1.0750x over previous
//
#include <hip/hip_runtime.h>
#include <math.h>

// PatchCore-DINOv2 anomaly score, round 10.
// Round-9 diagnosis: WRITE_SIZE 258MB = register spill (VGPR demand ~240 vs 128 avail,
// acc in AGPRs). Fix: consume B-frags in halves of 4 (peak VGPR ~105). Also: score
// writes subchunk-mins directly as float4 into [q][NSUBP] layout -> transpose kernel dropped.

#define D 384
#define PQ 256      // q rows per block
#define TNP 128     // bank rows per panel
#define BK 64       // k elems per chunk
#define LROW 72     // 144B LDS row stride: 2-way frag reads (free)

typedef __attribute__((ext_vector_type(8))) short short8v;
typedef __attribute__((ext_vector_type(4))) float f32x4;

static __device__ __forceinline__ unsigned short f2bf(float f) {
  unsigned u = __float_as_uint(f);
  unsigned r = 0x7FFFu + ((u >> 16) & 1u);   // RNE
  return (unsigned short)((u + r) >> 16);
}
static __device__ __forceinline__ unsigned pack2(float lo, float hi) {
  return (unsigned)f2bf(lo) | ((unsigned)f2bf(hi) << 16);
}

// ---------------- prep ----------------
__global__ void prep_kernel(const float* __restrict__ patches,
                            const float* __restrict__ globals_x,
                            float* __restrict__ pf32,
                            unsigned short* __restrict__ pbf,
                            float* __restrict__ psq,
                            float* __restrict__ gf32,
                            float* __restrict__ gsq,
                            int Q) {
  const int row = blockIdx.x;
  const int lane = threadIdx.x;  // 64 = 1 wave
  const float* src = (row < Q) ? (patches + (size_t)row * D)
                               : (globals_x + (size_t)(row - Q) * D);
  float v[6];
  float ss = 0.f;
#pragma unroll
  for (int j = 0; j < 6; ++j) { v[j] = src[lane + 64 * j]; ss += v[j] * v[j]; }
#pragma unroll
  for (int d = 1; d < 64; d <<= 1) ss += __shfl_xor(ss, d);
  const float inv = 1.f / (sqrtf(ss) + 1e-12f);
  float pn[6]; float ps = 0.f;
#pragma unroll
  for (int j = 0; j < 6; ++j) { pn[j] = v[j] * inv; ps += pn[j] * pn[j]; }
#pragma unroll
  for (int d = 1; d < 64; d <<= 1) ps += __shfl_xor(ps, d);
  if (row < Q) {
#pragma unroll
    for (int j = 0; j < 6; ++j) {
      pf32[(size_t)row * D + lane + 64 * j] = pn[j];
      pbf[(size_t)row * D + lane + 64 * j] = f2bf(pn[j]);
    }
    if (lane == 0) psq[row] = ps;
  } else {
    const int b = row - Q;
#pragma unroll
    for (int j = 0; j < 6; ++j) gf32[(size_t)b * D + lane + 64 * j] = pn[j];
    if (lane == 0) gsq[b] = ps;
  }
}

__device__ __forceinline__ void atomic_fmin(float* addr, float val) {
  unsigned* ua = (unsigned*)addr;
  float cur = __uint_as_float(atomicAdd(ua, 0u));
  while (val < cur) {
    unsigned assumed = __float_as_uint(cur);
    unsigned old = atomicCAS(ua, assumed, __float_as_uint(val));
    if (old == assumed) break;
    cur = __uint_as_float(old);
  }
}

// ---------------- score ----------------
// MODE 0: tilemin[q][NSUBP] subchunk mins via float4 store (main).
// MODE 1: atomic per-q min into tilemin[q] (low-ws fallback).
template <int MODE>
__global__ __launch_bounds__(256, 2) void score_kernel(
    const float* __restrict__ mbl,
    const unsigned short* __restrict__ pbf,
    float* __restrict__ tilemin,
    int Q, int N, int NSUBP, int QP, int q8, int r8) {
  __shared__ alignas(16) unsigned short lB0[TNP * LROW];
  __shared__ alignas(16) unsigned short lB1[TNP * LROW];
  __shared__ float msqH[TNP * 2];
  __shared__ float msqF[TNP];

  const int tid = threadIdx.x;
  const int lane = tid & 63;
  const int wid = tid >> 6;          // wave = 64q sub-tile
  const int fr = lane & 15;
  const int g = lane >> 4;

  // bijective XCD swizzle (m204): HW dispatch id -> logical wg, qp-fast
  const int flat = blockIdx.x;
  const int xcd = flat & 7, idx = flat >> 3;
  const int wg = (xcd < r8 ? xcd * (q8 + 1) : r8 * (q8 + 1) + (xcd - r8) * q8) + idx;
  const int nb = wg / QP;
  const int qp = wg - nb * QP;
  const int qbase = qp * PQ;
  const int nbase = nb * TNP;

  // B staging: thread t -> row t>>1, half t&1 (32 f32 per chunk)
  const int brow = tid >> 1, h = tid & 1;
  const int gn = nbase + brow;
  const float* bptr = mbl + (size_t)((gn < N) ? gn : 0) * D + h * 32;
  const int boff = brow * LROW + h * 32;

  // A: row = qbase + wid*64 + mf*16 + fr; elem = kc*64 + ks*32 + g*8
  const unsigned short* abase = pbf + (size_t)(qbase + wid * 64 + fr) * D + g * 8;

  f32x4 acc[4][8];
#pragma unroll
  for (int i = 0; i < 4; ++i)
#pragma unroll
    for (int j = 0; j < 8; ++j) acc[i][j] = (f32x4){0.f, 0.f, 0.f, 0.f};
  float msqreg = 0.f;
  float4 breg[8];
  short8v a[8];

  auto bload = [&](int kc) {
    const float* src = bptr + kc * BK;
#pragma unroll
    for (int i = 0; i < 8; ++i) breg[i] = *(const float4*)(src + i * 4);
  };
  auto bwrite = [&](unsigned short* base) {
    float s = 0.f;
    uint4 w[4];
#pragma unroll
    for (int i = 0; i < 4; ++i) {
      float4 f0 = breg[2 * i], f1 = breg[2 * i + 1];
      s += f0.x*f0.x + f0.y*f0.y + f0.z*f0.z + f0.w*f0.w
         + f1.x*f1.x + f1.y*f1.y + f1.z*f1.z + f1.w*f1.w;
      w[i] = (uint4){ pack2(f0.x,f0.y), pack2(f0.z,f0.w), pack2(f1.x,f1.y), pack2(f1.z,f1.w) };
    }
#pragma unroll
    for (int i = 0; i < 4; ++i) *(uint4*)(base + boff + i * 8) = w[i];
    msqreg += s;
  };
  auto aload = [&](int kc) {
#pragma unroll
    for (int ks = 0; ks < 2; ++ks)
#pragma unroll
      for (int mf = 0; mf < 4; ++mf)
        a[ks * 4 + mf] = *(const short8v*)(abase + (size_t)mf * 16 * D + kc * BK + ks * 32);
  };
  // B-frags consumed in halves of 4 -> peak live VGPRs ~105 (no spill; round-9 fix)
  auto compute = [&](const unsigned short* buf) {
#pragma unroll
    for (int ks = 0; ks < 2; ++ks) {
#pragma unroll
      for (int half = 0; half < 2; ++half) {
        short8v b4[4];
#pragma unroll
        for (int nf = 0; nf < 4; ++nf)
          b4[nf] = *(const short8v*)(&buf[((half * 4 + nf) * 16 + fr) * LROW + (ks * 4 + g) * 8]);
#pragma unroll
        for (int mf = 0; mf < 4; ++mf)
#pragma unroll
          for (int nf = 0; nf < 4; ++nf)
            acc[mf][half * 4 + nf] = __builtin_amdgcn_mfma_f32_16x16x32_bf16(
                a[ks * 4 + mf], b4[nf], acc[mf][half * 4 + nf], 0, 0, 0);
      }
    }
  };

  // prologue
  bload(0);
  bwrite(lB0);
  __syncthreads();
  // phases: [A-loads(k); B-loads(k+1); compute(k); vmcnt-drain+convert+write(k+1); barrier]
  aload(0); bload(1); compute(lB0); bwrite(lB1); __syncthreads();
  aload(1); bload(2); compute(lB1); bwrite(lB0); __syncthreads();
  aload(2); bload(3); compute(lB0); bwrite(lB1); __syncthreads();
  aload(3); bload(4); compute(lB1); bwrite(lB0); __syncthreads();
  aload(4); bload(5); compute(lB0); bwrite(lB1); __syncthreads();
  aload(5);           compute(lB1);              __syncthreads();

  // msq finalize (invalid rows -> +inf)
  msqH[tid] = msqreg;
  __syncthreads();
  if (tid < TNP) msqF[tid] = (nbase + tid < N) ? (msqH[2 * tid] + msqH[2 * tid + 1]) : 1e30f;
  __syncthreads();

  float mq[8];
#pragma unroll
  for (int nf = 0; nf < 8; ++nf) mq[nf] = msqF[nf * 16 + fr];

  // per-(q, 32-row subchunk) min; C: n = fr (within nf*16), q = g*4 + j
#pragma unroll
  for (int mf = 0; mf < 4; ++mf) {
#pragma unroll
    for (int j = 0; j < 4; ++j) {
      float v[4];
#pragma unroll
      for (int s = 0; s < 4; ++s)
        v[s] = fminf(mq[2 * s] - 2.f * acc[mf][2 * s][j],
                     mq[2 * s + 1] - 2.f * acc[mf][2 * s + 1][j]);
#pragma unroll
      for (int d2 = 1; d2 < 16; d2 <<= 1)
#pragma unroll
        for (int s = 0; s < 4; ++s) v[s] = fminf(v[s], __shfl_xor(v[s], d2));
      if (fr == 0) {
        const int q = qbase + wid * 64 + mf * 16 + g * 4 + j;
        if (MODE == 0) {
          // [q][NSUBP] layout, one aligned float4 per (q, panel)
          *(float4*)&tilemin[(size_t)q * NSUBP + nb * 4] =
              (float4){v[0], v[1], v[2], v[3]};
        } else {
          atomic_fmin(&tilemin[q],
                      fminf(fminf(v[0], v[1]), fminf(v[2], v[3])));
        }
      }
    }
  }
}

// ---------------- fallback helpers ----------------
__global__ void init_inf_kernel(float* __restrict__ p, int n) {
  int i = blockIdx.x * 256 + threadIdx.x;
  if (i < n) p[i] = 1e30f;
}
__global__ void final_dmin_kernel(const float* __restrict__ d2min,
                                  const float* __restrict__ psq,
                                  float* __restrict__ dmin, int Q) {
  int q = blockIdx.x * 256 + threadIdx.x;
  if (q < Q) dmin[q] = sqrtf(fmaxf(psq[q] + d2min[q], 0.f));
}

__device__ __forceinline__ float block_min(float v, float* red) {
#pragma unroll
  for (int d = 1; d < 64; d <<= 1) v = fminf(v, __shfl_xor(v, d));
  if ((threadIdx.x & 63) == 0) red[threadIdx.x >> 6] = v;
  __syncthreads();
  const float r = fminf(fminf(red[0], red[1]), fminf(red[2], red[3]));
  __syncthreads();
  return r;
}
__device__ __forceinline__ float block_max(float v, float* red) {
#pragma unroll
  for (int d = 1; d < 64; d <<= 1) v = fmaxf(v, __shfl_xor(v, d));
  if ((threadIdx.x & 63) == 0) red[threadIdx.x >> 6] = v;
  __syncthreads();
  const float r = fmaxf(fmaxf(red[0], red[1]), fmaxf(red[2], red[3]));
  __syncthreads();
  return r;
}

// ---------------- refine: coalesced scan of [q][NSUBP] + exact f32 on candidates ----------------
__global__ __launch_bounds__(256) void refine_kernel(
    const float* __restrict__ mbl,
    const float* __restrict__ pf32,
    const float* __restrict__ psq,
    const float* __restrict__ tm,    // [Q][NSUBP]
    float* __restrict__ dmin,
    int Q, int N, int NSUB, int NSUBP) {
  __shared__ int cnt;
  __shared__ int cand[64];
  __shared__ float red[4];
  const int q = blockIdx.x;
  const int tid = threadIdx.x;
  if (tid == 0) cnt = 0;
  __syncthreads();

  const float* rowp = tm + (size_t)q * NSUBP;
  float m = 1e30f;
  for (int r = tid; r < NSUB; r += 256) m = fminf(m, rowp[r]);
  const float gm = block_min(m, red);
  const float thr = gm + 0.25f;   // 2x margin over worst-case bf16 dot error

  for (int r = tid; r < NSUB; r += 256)
    if (rowp[r] <= thr) { int i = atomicAdd(&cnt, 1); if (i < 64) cand[i] = r; }
  __syncthreads();
  const int nc = min(cnt, 64);

  const int row8 = tid >> 3, oct = tid & 7;
  const float* prow = pf32 + (size_t)q * D + oct * 48;
  float4 pr[12];
#pragma unroll
  for (int i = 0; i < 12; ++i) pr[i] = *(const float4*)(prow + i * 4);

  float best = 1e30f;
  for (int c = 0; c < nc; ++c) {
    const int n = cand[c] * 32 + row8;
    float v;
    if (n < N) {
      const float* mr = mbl + (size_t)n * D + oct * 48;
      float dot = 0.f, ms = 0.f;
#pragma unroll
      for (int i = 0; i < 12; ++i) {
        float4 aa = *(const float4*)(mr + i * 4);
        dot += aa.x*pr[i].x + aa.y*pr[i].y + aa.z*pr[i].z + aa.w*pr[i].w;
        ms  += aa.x*aa.x + aa.y*aa.y + aa.z*aa.z + aa.w*aa.w;
      }
      v = ms - 2.f * dot;
    } else {
      v = 1e30f;
    }
#pragma unroll
    for (int d2 = 1; d2 < 8; d2 <<= 1) {
      float o = __shfl_xor(v, d2);
      v = (n < N) ? v + o : 1e30f;
    }
    best = fminf(best, v);
  }
  best = block_min(best, red);
  if (tid == 0) dmin[q] = sqrtf(fmaxf(psq[q] + best, 0.f));
}

// ---------------- global branch ----------------
__global__ __launch_bounds__(256) void gmin_kernel(
    const float* __restrict__ mbg,
    const float* __restrict__ gf32,
    const float* __restrict__ gsq,
    float* __restrict__ gpartG,
    int M) {
  __shared__ float red[4];
  const int b = blockIdx.x, s = blockIdx.y;
  const int tid = threadIdx.x;
  const int sl = (M + 31) / 32;
  const int row = s * sl + tid;
  const float* g = gf32 + (size_t)b * D;
  float v = 1e30f;
  if (tid < sl && row < M) {
    const float* mr = mbg + (size_t)row * D;
    float dot = 0.f, ms = 0.f;
#pragma unroll 4
    for (int k = 0; k < D; k += 4) {
      float4 aa = *(const float4*)(mr + k);
      float4 p = *(const float4*)(g + k);
      dot += aa.x*p.x + aa.y*p.y + aa.z*p.z + aa.w*p.w;
      ms  += aa.x*aa.x + aa.y*aa.y + aa.z*aa.z + aa.w*aa.w;
    }
    v = gsq[b] + ms - 2.f * dot;
  }
  v = block_min(v, red);
  if (tid == 0) gpartG[b * 32 + s] = v;
}

// ---------------- combine ----------------
__global__ __launch_bounds__(256) void out_kernel(
    const float* __restrict__ gpartG,
    const float* __restrict__ dmin,
    float* __restrict__ out,
    int P) {
  __shared__ float red[4];
  const int b = blockIdx.x;
  const int tid = threadIdx.x;
  float v = (tid < P) ? dmin[(size_t)b * P + tid] : -1e30f;
  const float local = block_max(v, red);
  float gm = (tid < 32) ? gpartG[b * 32 + tid] : 1e30f;
  gm = block_min(gm, red);
  if (tid == 0) out[b] = 0.7f * local + 0.3f * sqrtf(fmaxf(gm, 0.f));
}

extern "C" void kernel_launch(void* const* d_in, const int* in_sizes, int n_in,
                              void* d_out, int out_size, void* d_ws, size_t ws_size,
                              hipStream_t stream) {
  const float* patches   = (const float*)d_in[0];
  const float* globals_x = (const float*)d_in[1];
  const float* mbl       = (const float*)d_in[2];
  const float* mbg       = (const float*)d_in[3];
  float* out = (float*)d_out;

  const int Q = in_sizes[0] / D;          // 1024
  const int B = in_sizes[1] / D;          // 4
  const int N = in_sizes[2] / D;          // 100000
  const int M = in_sizes[3] / D;          // 2000
  const int P = Q / B;                    // 256
  const int NPAN = (N + TNP - 1) / TNP;   // 782
  const int NSUB = NPAN * 4;              // 3128
  const int NSUBP = ((NSUB + 63) / 64) * 64;  // 3136
  const int QP = (Q + PQ - 1) / PQ;       // 4
  const int nwg = QP * NPAN;              // 3128
  const int q8 = nwg / 8, r8 = nwg % 8;

  char* w = (char*)d_ws;
  char* wend = (char*)d_ws + ws_size;
  auto alloc = [&](size_t bytes) {
    char* p = w;
    w += (bytes + 255) & ~(size_t)255;
    return p;
  };
  float*          pf32   = (float*)alloc((size_t)Q * D * sizeof(float));
  unsigned short* pbf    = (unsigned short*)alloc((size_t)Q * D * sizeof(unsigned short));
  float*          psq    = (float*)alloc((size_t)Q * sizeof(float));
  float*          gf32   = (float*)alloc((size_t)B * D * sizeof(float));
  float*          gsqp   = (float*)alloc((size_t)B * sizeof(float));
  float*          dmin   = (float*)alloc((size_t)Q * sizeof(float));
  float*          gpartG = (float*)alloc((size_t)B * 32 * sizeof(float));
  float*          d2min  = (float*)alloc((size_t)Q * sizeof(float));
  if (w > wend) return;

  const size_t tm_bytes = (size_t)Q * NSUBP * sizeof(float);
  const int full = (w + ((tm_bytes + 255) & ~(size_t)255) <= wend) ? 1 : 0;

  prep_kernel<<<Q + B, 64, 0, stream>>>(patches, globals_x, pf32, pbf, psq, gf32, gsqp, Q);

  if (full) {
    float* tilemin = (float*)alloc(tm_bytes);
    score_kernel<0><<<nwg, 256, 0, stream>>>(mbl, pbf, tilemin, Q, N, NSUBP, QP, q8, r8);
    refine_kernel<<<Q, 256, 0, stream>>>(mbl, pf32, psq, tilemin, dmin, Q, N, NSUB, NSUBP);
  } else {
    init_inf_kernel<<<(Q + 255) / 256, 256, 0, stream>>>(d2min, Q);
    score_kernel<1><<<nwg, 256, 0, stream>>>(mbl, pbf, d2min, Q, N, NSUBP, QP, q8, r8);
    final_dmin_kernel<<<(Q + 255) / 256, 256, 0, stream>>>(d2min, psq, dmin, Q);
  }

  gmin_kernel<<<dim3(B, 32), 256, 0, stream>>>(mbg, gf32, gsqp, gpartG, M);
  out_kernel<<<B, 256, 0, stream>>>(gpartG, dmin, out, P);
}